// Round 1
// baseline (304.267 us; speedup 1.0000x reference)
//
#include <hip/hip_runtime.h>

typedef __attribute__((ext_vector_type(8))) short short8;
typedef __attribute__((ext_vector_type(4))) float f32x4;

#define NN 2048
#define NB 8
#define NG1 8
#define NF1 64
#define NT1 14
#define NT2 6
#define NK1 15
#define BNTOT 16384
#define KG2 448

static __device__ __forceinline__ unsigned short f2bf(float v) {
    union { float f; unsigned int u; } a; a.f = v;
    unsigned int u = a.u;
    u += 0x7fffu + ((u >> 16) & 1u);   // round-to-nearest-even
    return (unsigned short)(u >> 16);
}
static __device__ __forceinline__ float bf2f(unsigned short s) {
    union { float f; unsigned int u; } a; a.u = ((unsigned int)s) << 16;
    return a.f;
}
static __device__ __forceinline__ float sigmoidf_(float v) {
    return 1.f / (1.f + __expf(-v));
}

// ---------------------------------------------------------------------------
// prep: x (131072) and w2 (917504) fp32 -> bf16
// ---------------------------------------------------------------------------
__global__ __launch_bounds__(256) void prep_k(const float* __restrict__ x,
                                              const float* __restrict__ w2,
                                              unsigned short* __restrict__ xbf,
                                              unsigned short* __restrict__ w2bf) {
    const long total = 131072L + 917504L;
    for (long i = (long)blockIdx.x * 256 + threadIdx.x; i < total;
         i += (long)gridDim.x * 256) {
        if (i < 131072L) xbf[i] = f2bf(x[i]);
        else             w2bf[i - 131072L] = f2bf(w2[i - 131072L]);
    }
}

// ---------------------------------------------------------------------------
// GEMM: C[M,N] = A[M,K](bf16,row-major) @ B[K,N](fp32,row-major, batched by z)
//   A staged via global_load_lds (linear [BM][32] bf16 tile)
//   B staged reg-path: coalesced strided loads -> cvt bf16 -> LDS [BN][40]
// EPI 0: xS fp32 store (batch offset t*64*2048)
// EPI 1: z2 scatter store fp32
// EPI 2: +bias, sigmoid, bf16 -> h2
// ---------------------------------------------------------------------------
template <int BM, int BN, int EPI>
__global__ __launch_bounds__(256) void gemm_k(const unsigned short* __restrict__ A,
                                              int lda,
                                              const float* __restrict__ Bsrc,
                                              long ldb, long bstride, int K,
                                              void* __restrict__ outp,
                                              const float* __restrict__ bias) {
    constexpr int WM = BM / 2, WN = BN / 2;
    constexpr int MI = WM / 16, NI = WN / 16;
    constexpr int BKP = 40;  // padded K-stride (bf16 elems): 80B rows, 16B aligned
    __shared__ unsigned short Alds[BM * 32];
    __shared__ unsigned short Blds[BN * BKP];

    const int tid  = threadIdx.x;
    const int lane = tid & 63;
    const int wv   = tid >> 6;
    const int q    = lane >> 4;
    const int r    = lane & 15;
    const int wm   = (wv >> 1) * WM;
    const int wn   = (wv & 1) * WN;

    const int n0 = blockIdx.x * BN;
    const int m0 = blockIdx.y * BM;
    const int t  = blockIdx.z;

    const float* Bp = Bsrc + (long)t * bstride + n0;
    const unsigned short* Ap = A + (long)m0 * lda;

    f32x4 acc[MI][NI];
#pragma unroll
    for (int i = 0; i < MI; ++i)
#pragma unroll
        for (int j = 0; j < NI; ++j) acc[i][j] = (f32x4){0.f, 0.f, 0.f, 0.f};

    constexpr int ACH = BM / 64;       // 16B global_load_lds chunks per thread
    constexpr int BUN = BN * 8 / 256;  // (n, k-quad) units per thread

    for (int k0 = 0; k0 < K; k0 += 32) {
        // ---- A: direct global->LDS (wave-uniform base + lane*16) ----
#pragma unroll
        for (int c = 0; c < ACH; ++c) {
            const int row = (tid >> 2) + c * 64;
            const unsigned short* gp = Ap + (long)row * lda + k0 + (tid & 3) * 8;
            char* lb = (char*)Alds + c * 4096 + wv * 1024;  // wave-uniform
            __builtin_amdgcn_global_load_lds(
                (const __attribute__((address_space(1))) void*)gp,
                (__attribute__((address_space(3))) void*)lb, 16, 0, 0);
        }
        // ---- B: transpose+convert reg staging ----
#pragma unroll
        for (int u = 0; u < BUN; ++u) {
            const int idx = tid + u * 256;
            const int nl  = idx % BN;
            const int kq  = idx / BN;
            const float* bp = Bp + (long)(k0 + kq * 4) * ldb + nl;
            const float v0 = bp[0];
            const float v1 = bp[ldb];
            const float v2 = bp[2 * ldb];
            const float v3 = bp[3 * ldb];
            ushort4 pk;
            pk.x = f2bf(v0); pk.y = f2bf(v1); pk.z = f2bf(v2); pk.w = f2bf(v3);
            *(ushort4*)&Blds[nl * BKP + kq * 4] = pk;  // 8B store, aligned
        }
        __syncthreads();
        // ---- fragments + MFMA ----
        short8 af[MI];
        short8 bfv[NI];
#pragma unroll
        for (int i = 0; i < MI; ++i)
            af[i] = *(const short8*)&Alds[(wm + i * 16 + r) * 32 + q * 8];
#pragma unroll
        for (int j = 0; j < NI; ++j)
            bfv[j] = *(const short8*)&Blds[(wn + j * 16 + r) * BKP + q * 8];
#pragma unroll
        for (int i = 0; i < MI; ++i)
#pragma unroll
            for (int j = 0; j < NI; ++j)
                acc[i][j] = __builtin_amdgcn_mfma_f32_16x16x32_bf16(
                    af[i], bfv[j], acc[i][j], 0, 0, 0);
        __syncthreads();
    }

    // ---- epilogue: C[row][col], row=(lane>>4)*4+e in 16-subtile, col=lane&15
#pragma unroll
    for (int i = 0; i < MI; ++i) {
#pragma unroll
        for (int j = 0; j < NI; ++j) {
#pragma unroll
            for (int e = 0; e < 4; ++e) {
                const int row = m0 + wm + i * 16 + q * 4 + e;
                const int col = n0 + wn + j * 16 + r;
                const float v = acc[i][j][e];
                if constexpr (EPI == 0) {
                    float* o = (float*)outp + (long)t * (64 * 2048);
                    o[(long)row * 2048 + col] = v;
                } else if constexpr (EPI == 1) {
                    float* o = (float*)outp;
                    const int bb = row >> 6, gg = row & 63;
                    o[((long)((t + 1) * 64 + gg)) * BNTOT + bb * 2048 + col] = v;
                } else {
                    const float s = sigmoidf_(v + bias[row]);
                    ((unsigned short*)outp)[(long)row * BNTOT + col] = f2bf(s);
                }
            }
        }
    }
}

// ---------------------------------------------------------------------------
// combine1: out1[b,f,n] = sum_k sum_g z1[b,k,g,n]*w1[f,k,g] + b1[f]; h=sigmoid
// writes h -> A2 (bf16 [b*64+f][n]) and z2 k=0 rows (fp32 [f][b*2048+n])
// grid: (n-tiles of 128, b), 256 threads: n = tid&127, f-half = tid>>7
// ---------------------------------------------------------------------------
__global__ __launch_bounds__(256) void combine1_k(const float* __restrict__ x,
                                                  const float* __restrict__ xS,
                                                  const float* __restrict__ w1,
                                                  const float* __restrict__ b1,
                                                  unsigned short* __restrict__ A2,
                                                  float* __restrict__ z2) {
    __shared__ float w1s[NF1 * NK1 * NG1];  // 7680 floats = 30 KB
    const int tid = threadIdx.x;
    for (int i = tid; i < NF1 * NK1 * NG1; i += 256) w1s[i] = w1[i];
    __syncthreads();

    const int b  = blockIdx.y;
    const int n  = blockIdx.x * 128 + (tid & 127);
    const int fh = tid >> 7;  // 0/1 -> f in [fh*32, fh*32+32)

    float accv[32];
#pragma unroll
    for (int f = 0; f < 32; ++f) accv[f] = 0.f;

    for (int k = 0; k < NK1; ++k) {
        float vv[NG1];
#pragma unroll
        for (int g = 0; g < NG1; ++g) {
            if (k == 0) vv[g] = x[(long)(b * 8 + g) * 2048 + n];
            else vv[g] = xS[(long)(k - 1) * (64 * 2048) + (long)(b * 8 + g) * 2048 + n];
        }
#pragma unroll
        for (int f = 0; f < 32; ++f) {
            const float* wp = &w1s[((fh * 32 + f) * NK1 + k) * NG1];
            float s = 0.f;
#pragma unroll
            for (int g = 0; g < NG1; ++g) s += vv[g] * wp[g];
            accv[f] += s;
        }
    }
#pragma unroll
    for (int f = 0; f < 32; ++f) {
        const int fg = fh * 32 + f;
        const float h = sigmoidf_(accv[f] + b1[fg]);
        A2[(long)(b * 64 + fg) * 2048 + n] = f2bf(h);
        z2[(long)fg * BNTOT + b * 2048 + n] = h;
    }
}

// ---------------------------------------------------------------------------
// final: y[b,f,o] = |sigmoid(sum_n h2[f][b][n]*wlin[o][n] + blin[o])|
// one wave per (b,f) row
// ---------------------------------------------------------------------------
__global__ __launch_bounds__(256) void final_k(const unsigned short* __restrict__ h2,
                                               const float* __restrict__ wlin,
                                               const float* __restrict__ blin,
                                               float* __restrict__ out) {
    const int tid  = threadIdx.x;
    const int lane = tid & 63;
    const int wv   = tid >> 6;
    const long rowid = (long)blockIdx.x * 4 + wv;  // = f*8 + b
    const int f = (int)(rowid >> 3);
    const int b = (int)(rowid & 7);
    const unsigned short* hp = h2 + (long)f * BNTOT + b * 2048;

    float s0 = 0.f, s1 = 0.f;
    for (int it = 0; it < 4; ++it) {
        const int n = it * 512 + lane * 8;
        const short8 hv = *(const short8*)&hp[n];
#pragma unroll
        for (int j = 0; j < 8; ++j) {
            const float h = bf2f((unsigned short)hv[j]);
            s0 += h * wlin[n + j];
            s1 += h * wlin[2048 + n + j];
        }
    }
#pragma unroll
    for (int off = 32; off; off >>= 1) {
        s0 += __shfl_down(s0, off);
        s1 += __shfl_down(s1, off);
    }
    if (lane == 0) {
        out[(long)b * 4096 + f * 2 + 0] = fabsf(sigmoidf_(s0 + blin[0]));
        out[(long)b * 4096 + f * 2 + 1] = fabsf(sigmoidf_(s1 + blin[1]));
    }
}

// ---------------------------------------------------------------------------
extern "C" void kernel_launch(void* const* d_in, const int* in_sizes, int n_in,
                              void* d_out, int out_size, void* d_ws, size_t ws_size,
                              hipStream_t stream) {
    const float* x      = (const float*)d_in[0];
    const float* terms1 = (const float*)d_in[1];
    const float* terms2 = (const float*)d_in[2];
    const float* w1     = (const float*)d_in[3];
    const float* b1     = (const float*)d_in[4];
    const float* w2     = (const float*)d_in[5];
    const float* b2     = (const float*)d_in[6];
    const float* wlin   = (const float*)d_in[7];
    const float* blin   = (const float*)d_in[8];
    float* out = (float*)d_out;

    char* ws = (char*)d_ws;
    unsigned short* xbf  = (unsigned short*)(ws + 0);          //   262144 B
    unsigned short* w2bf = (unsigned short*)(ws + 262144);     //  1835008 B
    unsigned short* A2   = (unsigned short*)(ws + 2097152);    //  2097152 B
    float*          xS   = (float*)(ws + 4194304);             //  7340032 B
    float*          z2   = (float*)(ws + 11534336);            // 29360128 B
    unsigned short* h2   = (unsigned short*)(ws + 40894464);   // 67108864 B
    // total 108003328 B (~103 MB)

    // 1) fp32 -> bf16 for x and w2
    prep_k<<<1024, 256, 0, stream>>>(x, w2, xbf, w2bf);

    // 2) G1: xS[t] = x @ terms1[t]   (M=64, K=2048, N=2048, 14 batches)
    gemm_k<64, 64, 0><<<dim3(32, 1, 14), 256, 0, stream>>>(
        xbf, 2048, terms1, 2048L, 2048L * 2048L, 2048, (void*)xS, nullptr);

    // 3) combine layer 1 -> h (A2 bf16, z2 rows k=0 fp32)
    combine1_k<<<dim3(16, 8), 256, 0, stream>>>(x, xS, w1, b1, A2, z2);

    // 4) G2: hS[t] = h @ terms2[t]   (M=512, K=2048, N=2048, 6 batches) -> z2
    gemm_k<128, 128, 1><<<dim3(16, 4, 6), 256, 0, stream>>>(
        A2, 2048, terms2, 2048L, 2048L * 2048L, 2048, (void*)z2, nullptr);

    // 5) G3: h2 = sigmoid(w2 @ z2 + b2)  (M=2048, K=448, N=16384) bf16
    gemm_k<128, 128, 2><<<dim3(128, 16, 1), 256, 0, stream>>>(
        w2bf, 448, z2, 16384L, 0L, 448, (void*)h2, b2);

    // 6) final linear + sigmoid + abs
    final_k<<<4096, 256, 0, stream>>>(h2, wlin, blin, out);
}

// Round 2
// 282.599 us; speedup vs baseline: 1.0767x; 1.0767x over previous
//
#include <hip/hip_runtime.h>

typedef __attribute__((ext_vector_type(8))) short short8;
typedef __attribute__((ext_vector_type(4))) float f32x4;
typedef __attribute__((ext_vector_type(4))) unsigned short u16x4;

#define NN 2048
#define BNTOT 16384
#define KG2 448
#define NK1 15
#define NG1 8
#define NF1 64

static __device__ __forceinline__ unsigned short f2bf(float v) {
    union { float f; unsigned int u; } a; a.f = v;
    unsigned int u = a.u;
    u += 0x7fffu + ((u >> 16) & 1u);   // round-to-nearest-even
    return (unsigned short)(u >> 16);
}
static __device__ __forceinline__ float bf2f(unsigned short s) {
    union { float f; unsigned int u; } a; a.u = ((unsigned int)s) << 16;
    return a.f;
}
static __device__ __forceinline__ float sigmoidf_(float v) {
    return 1.f / (1.f + __expf(-v));
}

// ---------------------------------------------------------------------------
// prep: x (131072) and w2 (917504) fp32 -> bf16
// ---------------------------------------------------------------------------
__global__ __launch_bounds__(256) void prep_k(const float* __restrict__ x,
                                              const float* __restrict__ w2,
                                              unsigned short* __restrict__ xbf,
                                              unsigned short* __restrict__ w2bf) {
    const long total = 131072L + 917504L;
    for (long i = (long)blockIdx.x * 256 + threadIdx.x; i < total;
         i += (long)gridDim.x * 256) {
        if (i < 131072L) xbf[i] = f2bf(x[i]);
        else             w2bf[i - 131072L] = f2bf(w2[i - 131072L]);
    }
}

// ---------------------------------------------------------------------------
// transpose+convert: St[e][n][k] = bf16(S[e][k][n]) for e in {0,1}
// ---------------------------------------------------------------------------
__global__ __launch_bounds__(256) void transpose_k(const float* __restrict__ S,
                                                   unsigned short* __restrict__ St) {
    __shared__ float t[32][33];
    const int e  = blockIdx.z;
    const int n0 = blockIdx.x * 32, k0 = blockIdx.y * 32;
    const int tx = threadIdx.x & 31, ty = threadIdx.x >> 5;  // ty 0..7
    const float* src = S + (long)e * NN * NN;
    unsigned short* dst = St + (long)e * NN * NN;
#pragma unroll
    for (int i = 0; i < 4; ++i)
        t[ty + i * 8][tx] = src[(long)(k0 + ty + i * 8) * NN + n0 + tx];
    __syncthreads();
#pragma unroll
    for (int i = 0; i < 4; ++i)
        dst[(long)(n0 + ty + i * 8) * NN + k0 + tx] = f2bf(t[tx][ty + i * 8]);
}

// ---------------------------------------------------------------------------
// GEMM (m97 structure): C[M,N] = A[M,K](bf16 rm) @ Bt[N,K](bf16 rm)^T
// Both operands staged via global_load_lds (linear [.][32] bf16 tiles).
// Batch z: A slice = z>>a_shr (a_shr=30 -> const), B slice = z&1 (bstride=0 ok)
// EPI 0: bf16 store to outp + z*o_bstride, ld 2048
// EPI 1: z2t bf16 [col][448] scatter, slice kbase+z; optional chain bf16 rm
// EPI 2: +bias, sigmoid, bf16 -> h2 [row][16384]
// ---------------------------------------------------------------------------
template <int BM, int BN, int EPI>
__global__ __launch_bounds__(256) void gemm_k(
    const unsigned short* __restrict__ A, int lda, long a_bstride, int a_shr,
    const unsigned short* __restrict__ Bt, int ldb, long b_bstride,
    int K, void* __restrict__ outp, long o_bstride, int kbase,
    unsigned short* __restrict__ chain, const float* __restrict__ bias) {
    constexpr int WM = BM / 2, WN = BN / 2;
    constexpr int MI = WM / 16, NI = WN / 16;
    __shared__ unsigned short Alds[BM * 32];
    __shared__ unsigned short Blds[BN * 32];

    const int tid  = threadIdx.x;
    const int lane = tid & 63;
    const int wv   = tid >> 6;
    const int q    = lane >> 4;
    const int r    = lane & 15;
    const int wm   = (wv >> 1) * WM;
    const int wn   = (wv & 1) * WN;

    const int n0 = blockIdx.x * BN;
    const int m0 = blockIdx.y * BM;
    const int z  = blockIdx.z;

    const unsigned short* Ap = A + (long)(z >> a_shr) * a_bstride + (long)m0 * lda;
    const unsigned short* Bp = Bt + (long)(z & 1) * b_bstride + (long)n0 * ldb;

    f32x4 acc[MI][NI];
#pragma unroll
    for (int i = 0; i < MI; ++i)
#pragma unroll
        for (int j = 0; j < NI; ++j) acc[i][j] = (f32x4){0.f, 0.f, 0.f, 0.f};

    constexpr int ACH = BM / 64;
    constexpr int BCH = BN / 64;

    for (int k0 = 0; k0 < K; k0 += 32) {
#pragma unroll
        for (int c = 0; c < ACH; ++c) {
            const int row = (tid >> 2) + c * 64;
            const unsigned short* gp = Ap + (long)row * lda + k0 + (tid & 3) * 8;
            char* lb = (char*)Alds + c * 4096 + wv * 1024;  // wave-uniform base
            __builtin_amdgcn_global_load_lds(
                (const __attribute__((address_space(1))) void*)gp,
                (__attribute__((address_space(3))) void*)lb, 16, 0, 0);
        }
#pragma unroll
        for (int c = 0; c < BCH; ++c) {
            const int row = (tid >> 2) + c * 64;
            const unsigned short* gp = Bp + (long)row * ldb + k0 + (tid & 3) * 8;
            char* lb = (char*)Blds + c * 4096 + wv * 1024;
            __builtin_amdgcn_global_load_lds(
                (const __attribute__((address_space(1))) void*)gp,
                (__attribute__((address_space(3))) void*)lb, 16, 0, 0);
        }
        __syncthreads();
        short8 af[MI], bfv[NI];
#pragma unroll
        for (int i = 0; i < MI; ++i)
            af[i] = *(const short8*)&Alds[(wm + i * 16 + r) * 32 + q * 8];
#pragma unroll
        for (int j = 0; j < NI; ++j)
            bfv[j] = *(const short8*)&Blds[(wn + j * 16 + r) * 32 + q * 8];
#pragma unroll
        for (int i = 0; i < MI; ++i)
#pragma unroll
            for (int j = 0; j < NI; ++j)
                acc[i][j] = __builtin_amdgcn_mfma_f32_16x16x32_bf16(
                    af[i], bfv[j], acc[i][j], 0, 0, 0);
        __syncthreads();
    }

    // C/D layout: col = lane&15, row = (lane>>4)*4 + e  (m89-verified)
#pragma unroll
    for (int i = 0; i < MI; ++i) {
#pragma unroll
        for (int j = 0; j < NI; ++j) {
            const int row0 = m0 + wm + i * 16 + q * 4;
            const int col  = n0 + wn + j * 16 + r;
            if constexpr (EPI == 0) {
                unsigned short* o = (unsigned short*)outp + (long)z * o_bstride;
#pragma unroll
                for (int e = 0; e < 4; ++e)
                    o[(long)(row0 + e) * NN + col] = f2bf(acc[i][j][e]);
            } else if constexpr (EPI == 1) {
                const int bb = row0 >> 6, gg = row0 & 63;  // rows = b*64+g
                u16x4 pk;
                pk[0] = f2bf(acc[i][j][0]); pk[1] = f2bf(acc[i][j][1]);
                pk[2] = f2bf(acc[i][j][2]); pk[3] = f2bf(acc[i][j][3]);
                *(u16x4*)&((unsigned short*)outp)[
                    ((long)(bb * NN + col)) * KG2 + (kbase + z) * 64 + gg] = pk;
                if (chain) {
#pragma unroll
                    for (int e = 0; e < 4; ++e)
                        chain[(long)z * o_bstride + (long)(row0 + e) * NN + col] =
                            f2bf(acc[i][j][e]);
                }
            } else {
#pragma unroll
                for (int e = 0; e < 4; ++e) {
                    const float s = sigmoidf_(acc[i][j][e] + bias[row0 + e]);
                    ((unsigned short*)outp)[(long)(row0 + e) * BNTOT + col] = f2bf(s);
                }
            }
        }
    }
}

// ---------------------------------------------------------------------------
// combine1: h[b,f,n] = sigmoid(sum_k sum_g z1[b,k,g,n]*w1[f,k,g] + b1[f])
// z1 k=0 is x (fp32), k>=1 is xSbf (bf16). Writes A2 bf16 rm + z2t k=0 slice.
// ---------------------------------------------------------------------------
__global__ __launch_bounds__(256) void combine1_k(const float* __restrict__ x,
                                                  const unsigned short* __restrict__ xSbf,
                                                  const float* __restrict__ w1,
                                                  const float* __restrict__ b1,
                                                  unsigned short* __restrict__ A2,
                                                  unsigned short* __restrict__ z2t) {
    __shared__ float w1s[NF1 * NK1 * NG1];  // 7680 floats
    const int tid = threadIdx.x;
    for (int i = tid; i < NF1 * NK1 * NG1; i += 256) w1s[i] = w1[i];
    __syncthreads();

    const int b  = blockIdx.y;
    const int n  = blockIdx.x * 128 + (tid & 127);
    const int fh = tid >> 7;

    float accv[32];
#pragma unroll
    for (int f = 0; f < 32; ++f) accv[f] = 0.f;

    for (int k = 0; k < NK1; ++k) {
        float vv[NG1];
#pragma unroll
        for (int g = 0; g < NG1; ++g) {
            if (k == 0) vv[g] = x[(long)(b * 8 + g) * NN + n];
            else vv[g] = bf2f(xSbf[(long)(k - 1) * (64 * 2048) +
                                   (long)(b * 8 + g) * NN + n]);
        }
#pragma unroll
        for (int f = 0; f < 32; ++f) {
            const float* wp = &w1s[((fh * 32 + f) * NK1 + k) * NG1];
            float s = 0.f;
#pragma unroll
            for (int g = 0; g < NG1; ++g) s += vv[g] * wp[g];
            accv[f] += s;
        }
    }
    unsigned short hb[32];
#pragma unroll
    for (int f = 0; f < 32; ++f) {
        const int fg = fh * 32 + f;
        const float h = sigmoidf_(accv[f] + b1[fg]);
        hb[f] = f2bf(h);
        A2[(long)(b * 64 + fg) * NN + n] = hb[f];
    }
    const long zb = ((long)(b * NN + n)) * KG2 + fh * 32;
#pragma unroll
    for (int c = 0; c < 4; ++c)
        *(short8*)&z2t[zb + c * 8] = *(const short8*)&hb[c * 8];
}

// ---------------------------------------------------------------------------
// final: y[b,f,o] = |sigmoid(sum_n h2[f][b*2048+n]*wlin[o][n] + blin[o])|
// ---------------------------------------------------------------------------
__global__ __launch_bounds__(256) void final_k(const unsigned short* __restrict__ h2,
                                               const float* __restrict__ wlin,
                                               const float* __restrict__ blin,
                                               float* __restrict__ out) {
    const int tid  = threadIdx.x;
    const int lane = tid & 63;
    const int wv   = tid >> 6;
    const long rowid = (long)blockIdx.x * 4 + wv;  // = f*8 + b
    const int f = (int)(rowid >> 3);
    const int b = (int)(rowid & 7);
    const unsigned short* hp = h2 + (long)f * BNTOT + b * NN;

    float s0 = 0.f, s1 = 0.f;
    for (int it = 0; it < 4; ++it) {
        const int n = it * 512 + lane * 8;
        const short8 hv = *(const short8*)&hp[n];
#pragma unroll
        for (int j = 0; j < 8; ++j) {
            const float h = bf2f((unsigned short)hv[j]);
            s0 += h * wlin[n + j];
            s1 += h * wlin[NN + n + j];
        }
    }
#pragma unroll
    for (int off = 32; off; off >>= 1) {
        s0 += __shfl_down(s0, off);
        s1 += __shfl_down(s1, off);
    }
    if (lane == 0) {
        out[(long)b * 4096 + f * 2 + 0] = fabsf(sigmoidf_(s0 + blin[0]));
        out[(long)b * 4096 + f * 2 + 1] = fabsf(sigmoidf_(s1 + blin[1]));
    }
}

// ---------------------------------------------------------------------------
extern "C" void kernel_launch(void* const* d_in, const int* in_sizes, int n_in,
                              void* d_out, int out_size, void* d_ws, size_t ws_size,
                              hipStream_t stream) {
    const float* x      = (const float*)d_in[0];
    const float* terms1 = (const float*)d_in[1];  // slices 0,1 are S0,S1
    const float* w1     = (const float*)d_in[3];
    const float* b1     = (const float*)d_in[4];
    const float* w2     = (const float*)d_in[5];
    const float* b2     = (const float*)d_in[6];
    const float* wlin   = (const float*)d_in[7];
    const float* blin   = (const float*)d_in[8];
    float* out = (float*)d_out;

    char* ws = (char*)d_ws;
    unsigned short* xbf   = (unsigned short*)(ws + 0);          //   262144 B
    unsigned short* w2bf  = (unsigned short*)(ws + 262144);     //  1835008 B
    unsigned short* St    = (unsigned short*)(ws + 2097152);    // 16777216 B
    unsigned short* xSbf  = (unsigned short*)(ws + 18874368);   //  3670016 B
    unsigned short* A2    = (unsigned short*)(ws + 22544384);   //  2097152 B
    unsigned short* hS1bf = (unsigned short*)(ws + 24641536);   //  4194304 B
    unsigned short* z2t   = (unsigned short*)(ws + 28835840);   // 14680064 B
    unsigned short* h2    = (unsigned short*)(ws + 43515904);   // 67108864 B
    // total 110624768 B (~105 MB)

    const long SLICE = (long)NN * NN;       // S batch stride (elems)
    const long XSL   = 64L * 2048;          // xS slice stride
    const long HSL   = 512L * 2048;         // hS1 slice stride

    // 1) fp32 -> bf16 (x, w2); S0,S1 -> bf16 transposed [n][k]
    prep_k<<<1024, 256, 0, stream>>>(x, w2, xbf, w2bf);
    transpose_k<<<dim3(64, 64, 2), 256, 0, stream>>>(terms1, St);

    // 2) G1 chain: order 1, 2, 3  (M=64, N=2048, K=2048)
    gemm_k<64, 64, 0><<<dim3(32, 1, 2), 256, 0, stream>>>(
        xbf, NN, 0L, 30, St, NN, SLICE, NN, (void*)xSbf, XSL, 0, nullptr, nullptr);
    gemm_k<64, 64, 0><<<dim3(32, 1, 4), 256, 0, stream>>>(
        xSbf, NN, XSL, 1, St, NN, SLICE, NN, (void*)(xSbf + 2 * XSL), XSL, 0,
        nullptr, nullptr);
    gemm_k<64, 64, 0><<<dim3(32, 1, 8), 256, 0, stream>>>(
        xSbf + 2 * XSL, NN, XSL, 1, St, NN, SLICE, NN, (void*)(xSbf + 6 * XSL),
        XSL, 0, nullptr, nullptr);

    // 3) layer-1 combine -> A2 (bf16 rm) + z2t k=0
    combine1_k<<<dim3(16, 8), 256, 0, stream>>>(x, xSbf, w1, b1, A2, z2t);

    // 4) G2 chain: hS1 = h@S (z2t k=1..2 + chain), hS2 = hS1@S (z2t k=3..6)
    gemm_k<128, 128, 1><<<dim3(16, 4, 2), 256, 0, stream>>>(
        A2, NN, 0L, 30, St, NN, SLICE, NN, (void*)z2t, HSL, 1, hS1bf, nullptr);
    gemm_k<128, 128, 1><<<dim3(16, 4, 4), 256, 0, stream>>>(
        hS1bf, NN, HSL, 1, St, NN, SLICE, NN, (void*)z2t, 0L, 3, nullptr, nullptr);

    // 5) G3: h2 = sigmoid(w2 @ z2 + b2)  (M=2048, K=448, N=16384)
    gemm_k<128, 128, 2><<<dim3(128, 16, 1), 256, 0, stream>>>(
        w2bf, KG2, 0L, 30, z2t, KG2, 0L, KG2, (void*)h2, 0L, 0, nullptr, b2);

    // 6) final linear + sigmoid + abs
    final_k<<<4096, 256, 0, stream>>>(h2, wlin, blin, out);
}